// Round 8
// baseline (259.551 us; speedup 1.0000x reference)
//
#include <hip/hip_runtime.h>

#define HDIM 4096
#define NIN 17
#define NA 4

using f4 = __attribute__((ext_vector_type(4))) float;

// ---- config ----
constexpr int TB = 256;                 // threads per block
constexpr int CPT = 4;                  // columns per thread (one float4)
constexpr int BXC = HDIM / (TB * CPT);  // 4 column groups
constexpr int NCHUNK = 512;             // row chunks (2048 blocks total)
constexpr int RPC = HDIM / NCHUNK;      // 8 rows per chunk
constexpr size_t NELEM = (size_t)HDIM * HDIM;

// Kernel A: partial sums of hidden @ (w + alpha*hebb).
// 24-float4 load burst pinned live via sched_barrier(0); launch_bounds(256,2)
// raises the VGPR cap to 256 so regalloc CAN keep the burst in flight
// (previous rounds: compiler allocated 28-40 VGPR and serialized the loads).
// w/alpha NONTEMPORAL (single-use; keeps 64 MB hebb L3-resident across
// iterations - R3/R7 measured FETCH 98 MB of 200 MB touched).
__global__ __launch_bounds__(TB, 2)
void k_matvec(const float* __restrict__ w, const float* __restrict__ alpha,
              const float* __restrict__ hebb, const float* __restrict__ hidden,
              float* __restrict__ partial, float* __restrict__ acc5,
              unsigned* __restrict__ cnt) {
    if (blockIdx.x == 0 && blockIdx.y == 0 && threadIdx.x < 9) {
        if (threadIdx.x < 8) acc5[threadIdx.x] = 0.f;
        else *cnt = 0u;
    }
    const int col0 = (blockIdx.x * TB + threadIdx.x) * CPT;
    const int row0 = blockIdx.y * RPC;
    const size_t base = (size_t)row0 * HDIM + col0;

    f4 wv[RPC], av[RPC], bv[RPC];
#pragma unroll
    for (int r = 0; r < RPC; ++r) {
        const size_t off = base + (size_t)r * HDIM;
        wv[r] = __builtin_nontemporal_load((const f4*)(w + off));
        av[r] = __builtin_nontemporal_load((const f4*)(alpha + off));
        bv[r] = *(const f4*)(hebb + off);
    }
    __builtin_amdgcn_sched_barrier(0);   // no FMA may move above: all 24 loads in flight

    f4 acc = {0.f, 0.f, 0.f, 0.f};
#pragma unroll
    for (int r = 0; r < RPC; ++r) {
        const float hv = hidden[row0 + r];
        acc += hv * (wv[r] + av[r] * bv[r]);
    }
    *(f4*)(partial + (size_t)blockIdx.y * HDIM + col0) = acc;
}

// Kernel B: reduce 512 partials per column -> h = tanh(i2h + matvec);
// fused heads (shfl + atomicAdd) + last-block softmax/value finalize.
constexpr int HC = 32;                // cols per block
constexpr int HGRP = TB / HC;         // 8 groups
constexpr int HCPG = NCHUNK / HGRP;   // 64 chunks per group

__global__ void k_hact(const float* __restrict__ partial, const float* __restrict__ x,
                       const float* __restrict__ i2h_w, const float* __restrict__ i2h_b,
                       const float* __restrict__ h2o_w, const float* __restrict__ h2o_b,
                       const float* __restrict__ h2v_w, const float* __restrict__ h2v_b,
                       float* __restrict__ h_f, float* __restrict__ h_out,
                       float* __restrict__ acc5, unsigned* __restrict__ cnt,
                       float* __restrict__ out) {
    const int tid = threadIdx.x;
    const int lane = tid & (HC - 1);
    const int grp = tid >> 5;
    const int col = blockIdx.x * HC + lane;

    float s = 0.f;
    const float* p = partial + (size_t)(grp * HCPG) * HDIM + col;
#pragma unroll 16
    for (int c = 0; c < HCPG; ++c) s += p[(size_t)c * HDIM];

    __shared__ float red[TB];
    red[tid] = s;
    __syncthreads();
    for (int st = TB / 2; st >= HC; st >>= 1) {
        if (tid < st) red[tid] += red[tid + st];
        __syncthreads();
    }
    if (tid < HC) {
        float z = red[tid] + i2h_b[col];
#pragma unroll
        for (int k = 0; k < NIN; ++k) z += x[k] * i2h_w[col * NIN + k];
        const float h = tanhf(z);
        h_f[col] = h;
        h_out[col] = h;
        float d[NA + 1];
#pragma unroll
        for (int a = 0; a < NA; ++a) d[a] = h * h2o_w[(size_t)a * HDIM + col];
        d[NA] = h * h2v_w[col];
#pragma unroll
        for (int a = 0; a <= NA; ++a) {
            float v = d[a];
#pragma unroll
            for (int sft = 16; sft > 0; sft >>= 1) v += __shfl_down(v, sft, 32);
            if (lane == 0) atomicAdd(acc5 + a, v);
        }
    }
    // last-block finalize (R6-proven): removes the k_finish dispatch
    if (tid == 0) {
        __threadfence();
        if (atomicAdd(cnt, 1u) == (HDIM / HC) - 1) {
            float res[NA + 1];
#pragma unroll
            for (int a = 0; a <= NA; ++a) res[a] = atomicAdd(acc5 + a, 0.f);
            float o[NA];
            float mx = -1e30f;
#pragma unroll
            for (int a = 0; a < NA; ++a) { o[a] = res[a] + h2o_b[a]; mx = fmaxf(mx, o[a]); }
            float se = 0.f;
#pragma unroll
            for (int a = 0; a < NA; ++a) { o[a] = __expf(o[a] - mx); se += o[a]; }
#pragma unroll
            for (int a = 0; a < NA; ++a) out[a] = o[a] / se;
            out[NA] = res[NA] + h2v_b[0];
        }
    }
}

// Kernel C: hebb_new = (1-eta)*hebb + eta*outer(hidden, h).
// Shuffle-realign: out-quad k (elements s..s+3, s=4k+3) needs hebb[4k+3..4k+6]
// = {A_k.w, A_{k+1}.xyz} where A_k = aligned float4 at hebb+4k. Lane l holds
// A_k; lane l+1 holds A_{k+1} -> 3 shfl_down replace the misaligned scalar+f4
// load pair. Per 16 B output: 1 aligned f4 load + 1 aligned NT f4 store.
// Lane 63 fixes up A_{k+1} with a direct (predicated) load.
constexpr size_t NQK = (NELEM - 4) / 4;   // 4194303 output quads
constexpr int HEB_BLK = 4096;             // x 256 threads x 4 quads >= NQK

__global__ void k_hebb(const float* __restrict__ hebb, const float* __restrict__ hidden,
                       const float* __restrict__ h_f, const float* __restrict__ eta,
                       float* __restrict__ hebb_out) {
    const int tid = threadIdx.x;
    const size_t gt = (size_t)blockIdx.x * TB + tid;
    const size_t wid = gt >> 6;           // global wave id
    const int lane = tid & 63;
    const float e = eta[0];
    const float om = 1.f - e;

    if (gt == 0) {  // head elements 0,1,2 (row 0) + tail element NELEM-1
        const float hv0 = e * hidden[0];
        hebb_out[0] = om * hebb[0] + hv0 * h_f[0];
        hebb_out[1] = om * hebb[1] + hv0 * h_f[1];
        hebb_out[2] = om * hebb[2] + hv0 * h_f[2];
        hebb_out[NELEM - 1] = om * hebb[NELEM - 1] + e * hidden[HDIM - 1] * h_f[HDIM - 1];
    }

    // 4 quads/thread, wave-contiguous: wave covers 256 consecutive quads.
    size_t k[4];
    bool ok[4];
    f4 A[4];
#pragma unroll
    for (int q = 0; q < 4; ++q) {
        k[q] = wid * 256 + (size_t)lane + (size_t)q * 64;
        ok[q] = k[q] < NQK;
        // A-load always in-bounds: max 4*k[q] = 4*NQK = NELEM-4.
        A[q] = *(const f4*)(hebb + 4 * k[q]);
    }
    __builtin_amdgcn_sched_barrier(0);    // all 4 A-loads in flight

    f4 B[4];
#pragma unroll
    for (int q = 0; q < 4; ++q) {         // A_{k+1} from lane l+1
        B[q].x = __shfl_down(A[q].x, 1, 64);
        B[q].y = __shfl_down(A[q].y, 1, 64);
        B[q].z = __shfl_down(A[q].z, 1, 64);
        B[q].w = 0.f;
    }
    if (lane == 63) {                     // fixup: next wave's first vector
#pragma unroll
        for (int q = 0; q < 4; ++q)
            if (ok[q]) B[q] = *(const f4*)(hebb + 4 * (k[q] + 1));
    }

#pragma unroll
    for (int q = 0; q < 4; ++q) {
        if (ok[q]) {
            const size_t s = 4 * k[q] + 3;
            const float b[4] = {A[q].w, B[q].x, B[q].y, B[q].z};
            f4 v;
#pragma unroll
            for (int kk = 0; kk < 4; ++kk) {
                const size_t m = s + (size_t)kk;
                const int i = (int)(m >> 12);
                const int jj = (int)(m & (HDIM - 1));
                v[kk] = om * b[kk] + e * hidden[i] * h_f[jj];
            }
            __builtin_nontemporal_store(v, (f4*)(hebb_out + s));  // 16B-aligned
        }
    }
}

extern "C" void kernel_launch(void* const* d_in, const int* in_sizes, int n_in,
                              void* d_out, int out_size, void* d_ws, size_t ws_size,
                              hipStream_t stream) {
    const float* x      = (const float*)d_in[0];
    const float* hidden = (const float*)d_in[1];
    const float* hebb   = (const float*)d_in[2];
    const float* i2h_w  = (const float*)d_in[3];
    const float* i2h_b  = (const float*)d_in[4];
    const float* w      = (const float*)d_in[5];
    const float* alpha  = (const float*)d_in[6];
    const float* eta    = (const float*)d_in[7];
    const float* h2o_w  = (const float*)d_in[8];
    const float* h2o_b  = (const float*)d_in[9];
    const float* h2v_w  = (const float*)d_in[10];
    const float* h2v_b  = (const float*)d_in[11];
    float* out = (float*)d_out;

    // out layout: activout[4] | valueout[1] | h[4096] | hebb_new[4096*4096]
    float* h_out    = out + 5;
    float* hebb_out = out + 5 + HDIM;

    // partial[NCHUNK][HDIM] (8 MB) in the hebb_out region as scratch:
    // consumed by k_hact, then fully overwritten by k_hebb (R3/R7-proven).
    float* partial = out + 8192;

    float* h_f  = (float*)d_ws;        // HDIM floats
    float* acc5 = h_f + HDIM;          // 8 floats (5 used)
    unsigned* cnt = (unsigned*)(acc5 + 8);

    k_matvec<<<dim3(BXC, NCHUNK), TB, 0, stream>>>(w, alpha, hebb, hidden, partial, acc5, cnt);
    k_hact<<<HDIM / HC, TB, 0, stream>>>(partial, x, i2h_w, i2h_b, h2o_w, h2o_b,
                                         h2v_w, h2v_b, h_f, h_out, acc5, cnt, out);
    k_hebb<<<HEB_BLK, TB, 0, stream>>>(hebb, hidden, h_f, eta, hebb_out);
}